// Round 13
// baseline (305.686 us; speedup 1.0000x reference)
//
#include <hip/hip_runtime.h>
#include <hip/hip_bf16.h>
#include <stdint.h>

#define N_NODES 50000
#define N_EDGES 200000
#define NODE_F 64
#define EDGE_F 16
#define HID 32
#define LAT 16
#define KTOT 1056   // 1024 + 32 (b2 folded in as 33rd K-tile)
#define SCAN_BLOCKS 196   // 196*256 = 50176 >= 50000

typedef __attribute__((ext_vector_type(8))) short short8;   // 8 bf16 = 4 VGPR
typedef __attribute__((ext_vector_type(4))) float f32x4;
typedef __attribute__((ext_vector_type(2))) float f32x2;

static __device__ __forceinline__ unsigned short bfbits(float f) {
  union { __hip_bfloat16 h; unsigned short s; } c; c.h = __float2bfloat16(f); return c.s;
}
// Truncation pack: 1x v_perm_b32. lo16 = top of bits(v.x), hi16 = top of bits(v.y).
static __device__ __forceinline__ unsigned pkt(f32x2 v) {
  return __builtin_amdgcn_perm(__float_as_uint(v.y), __float_as_uint(v.x), 0x07060302u);
}
union AFrag { short8 v; unsigned u[4]; };

// --- prep: w2 transpose to bf16 B-layout, w1 packed into per-lane B-fragments,
//     deg zeroing (all fused, once per call) ---
__global__ void k_prep(const float* __restrict__ ew2, const float* __restrict__ eb2,
                       const float* __restrict__ ew1,
                       unsigned short* __restrict__ w2t,
                       unsigned short* __restrict__ w1p,
                       int* __restrict__ deg) {
  int g = blockIdx.x*256 + threadIdx.x;          // 396*256 = 101376 exactly
  int l = g / (HID*KTOT);
  int r = g % (HID*KTOT);
  int o = r / KTOT;
  int kg = r % KTOT;
  int k = kg >> 5, h = kg & 31;
  float v = (k < 32) ? ew2[(size_t)l*32768 + k*1024 + h*32 + o]
                     : eb2[(size_t)l*1024 + h*32 + o];
  w2t[g] = bfbits(v);
  if (g < N_NODES) deg[g] = 0;
  // w1p[l][nt][lane][j] = B-frag element B[k=(lane>>4)*8+j][n=nt*16+(lane&15)]
  if (g < 3*2*64*8) {
    int l2 = g >> 10;
    int r2 = g & 1023;
    int nt = r2 >> 9;
    int ln = (r2 >> 3) & 63;
    int j  = r2 & 7;
    int kgr = ln >> 4;
    float w = (kgr < 2) ? ew1[(size_t)l2*512 + (kgr*8 + j)*32 + nt*16 + (ln & 15)] : 0.f;
    w1p[g] = bfbits(w);
  }
}

__global__ void k_hist(const int* __restrict__ ei, int* __restrict__ deg) {
  int t = blockIdx.x*256 + threadIdx.x;
  if (t >= N_EDGES) return;
  int d = ei[N_EDGES + t];
  d = min(max(d, 0), N_NODES-1);
  atomicAdd(&deg[d], 1);
}

__global__ __launch_bounds__(256) void k_scan1(const int* __restrict__ deg,
                                               int* __restrict__ off,
                                               int* __restrict__ bsum) {
  __shared__ int s[256];
  const int tid = threadIdx.x;
  const int t = blockIdx.x*256 + tid;
  int d = (t < N_NODES) ? deg[t] : 0;
  s[tid] = d; __syncthreads();
  int v = d;
  #pragma unroll
  for (int ofs = 1; ofs < 256; ofs <<= 1) {
    int w = (tid >= ofs) ? s[tid-ofs] : 0;
    __syncthreads();
    v += w; s[tid] = v;
    __syncthreads();
  }
  if (t < N_NODES) off[t] = v - d;
  if (tid == 255) bsum[blockIdx.x] = v;
}

// fused scan2+scan3: each block computes its bsum prefix in-wave, applies, zeroes cursor
__global__ __launch_bounds__(256) void k_scan23(int* __restrict__ off,
                                                const int* __restrict__ bsum,
                                                int* __restrict__ cursor) {
  __shared__ int sPref;
  const int tid = threadIdx.x;
  const int b = blockIdx.x;
  if (tid < 64) {
    int acc = 0;
    for (int i = tid; i < b; i += 64) acc += bsum[i];
    #pragma unroll
    for (int o = 32; o; o >>= 1) acc += __shfl_down(acc, o);
    if (tid == 0) sPref = acc;
  }
  __syncthreads();
  int pref = sPref;
  int t = b*256 + tid;
  if (t < N_NODES) {
    off[t] += pref;
    cursor[t] = 0;
  }
  if (t == 0) off[N_NODES] = N_EDGES;
}

// emits csr_pos only: csr_pos[e] = slot of edge e in CSR order
__global__ void k_scatter(const int* __restrict__ ei, const int* __restrict__ off,
                          int* __restrict__ cursor, int* __restrict__ csr_pos) {
  int t = blockIdx.x*256 + threadIdx.x;
  if (t >= N_EDGES) return;
  int d = ei[N_EDGES + t];
  d = min(max(d, 0), N_NODES-1);
  int pos = atomicAdd(&cursor[d], 1);
  csr_pos[t] = off[d] + pos;
}

// h = relu(x @ W + b)
__global__ void k_lin_in(const float* __restrict__ x,
                         const float* __restrict__ W,
                         const float* __restrict__ b,
                         float* __restrict__ h) {
  __shared__ float Ws[NODE_F*HID];
  __shared__ float bs[HID];
  for (int i = threadIdx.x; i < NODE_F*HID; i += 256) Ws[i] = W[i];
  if (threadIdx.x < HID) bs[threadIdx.x] = b[threadIdx.x];
  __syncthreads();
  int t = blockIdx.x*256 + threadIdx.x;
  if (t >= N_NODES*HID) return;
  int n = t >> 5, o = t & 31;
  const float4* xp = (const float4*)(x + (size_t)n*NODE_F);
  float acc = bs[o];
  #pragma unroll
  for (int j = 0; j < NODE_F/4; j++) {
    float4 v = xp[j];
    acc = fmaf(v.x, Ws[(4*j+0)*HID+o], acc);
    acc = fmaf(v.y, Ws[(4*j+1)*HID+o], acc);
    acc = fmaf(v.z, Ws[(4*j+2)*HID+o], acc);
    acc = fmaf(v.w, Ws[(4*j+3)*HID+o], acc);
  }
  h[t] = fmaxf(acc, 0.f);
}

// MFMA msg kernel, K-split: 64 edges/block (3125 blocks), 4 waves.
// wave w: nhalf=w&1 (16 outputs), khalf=w>>1 (K rows [khalf*16, khalf*16+16); khalf0 adds bias row 32).
// Waves 0-1 stage he via MFMA; khalf1 partials reduced via LDS into khalf0; bf16 store in CSR order.
__global__ __launch_bounds__(256) void k_msg(const float* __restrict__ hin,
                                             const float* __restrict__ ea,
                                             const int* __restrict__ ei,
                                             const unsigned short* __restrict__ w1pl,
                                             const float* __restrict__ b1,
                                             const unsigned short* __restrict__ w2tl,
                                             const int* __restrict__ csr_pos,
                                             unsigned short* __restrict__ msgB) {
  __shared__ float sHE[64*33];        // 8.4 KB
  __shared__ float sRED[2*64*17];     // 8.7 KB (stride 17 breaks bank conflicts)
  __shared__ int   sSRC[64];
  __shared__ int   sPOS[64];
  const int tid = threadIdx.x;
  const int be  = blockIdx.x*64;      // grid exact: 200000 = 3125*64
  const int wv   = tid >> 6;
  const int lane = tid & 63;
  const int nn   = lane & 15;
  const int quad = lane >> 4;
  const int nhalf = wv & 1;
  const int khalf = wv >> 1;

  if (tid < 64) {
    int e = be + tid;
    sSRC[tid] = min(max(ei[e], 0), N_NODES-1);
    sPOS[tid] = csr_pos[e];
    sHE[tid*33 + 32] = 1.0f;          // bias K-row
  }

  // --- he via MFMA (waves 0,1 only; wave w covers tiles 2w, 2w+1) ---
  if (khalf == 0) {
    short8 wb0 = *(const short8*)(w1pl + lane*8);         // nt=0
    short8 wb1 = *(const short8*)(w1pl + 512 + lane*8);   // nt=1
    f32x4 z = {0.f,0.f,0.f,0.f};
    float bv0 = b1[nn], bv1 = b1[nn + 16];
    #pragma unroll
    for (int ti = 0; ti < 2; ti++) {
      int t = nhalf*2 + ti;
      AFrag a;
      if (quad < 2) {
        int e = be + t*16 + nn;
        const float4* p = (const float4*)(ea + (size_t)e*EDGE_F + quad*8);
        float4 u = p[0], v = p[1];
        a.u[0] = pkt(f32x2{u.x,u.y}); a.u[1] = pkt(f32x2{u.z,u.w});
        a.u[2] = pkt(f32x2{v.x,v.y}); a.u[3] = pkt(f32x2{v.z,v.w});
      } else {
        #pragma unroll
        for (int i = 0; i < 4; i++) a.u[i] = 0u;
      }
      f32x4 h0 = __builtin_amdgcn_mfma_f32_16x16x32_bf16(a.v, wb0, z, 0, 0, 0);
      f32x4 h1 = __builtin_amdgcn_mfma_f32_16x16x32_bf16(a.v, wb1, z, 0, 0, 0);
      #pragma unroll
      for (int r = 0; r < 4; r++) {
        int ro = (t*16 + quad*4 + r)*33;
        sHE[ro + nn]      = fmaxf(h0[r] + bv0, 0.f);
        sHE[ro + 16 + nn] = fmaxf(h1[r] + bv1, 0.f);
      }
    }
  }
  __syncthreads();

  // xs from global (L2-hot), 4 M-tiles (shared edges across waves)
  f32x2 xs[4][4];
  #pragma unroll
  for (int t = 0; t < 4; t++) {
    int si = sSRC[t*16 + nn];
    const float4* p = (const float4*)(hin + (size_t)si*HID);
    float4 a = p[quad*2], b = p[quad*2+1];
    xs[t][0] = f32x2{a.x, a.y}; xs[t][1] = f32x2{a.z, a.w};
    xs[t][2] = f32x2{b.x, b.y}; xs[t][3] = f32x2{b.z, b.w};
  }

  f32x4 c[4];
  #pragma unroll
  for (int t = 0; t < 4; t++) c[t] = f32x4{0.f,0.f,0.f,0.f};

  const int k0 = khalf*16;
  const unsigned short* bp = w2tl + (unsigned)nn*KTOT + quad*8 + (unsigned)nhalf*(16*KTOT);
  const float* heR[4];
  #pragma unroll
  for (int t = 0; t < 4; t++) heR[t] = sHE + (t*16 + nn)*33;

  // depth-3 pipeline; uniform steps s=0..16, kk = (s>=16 ? 32 : k0+s); khalf1 skips s=16
  short8 sb[3];
  float  sh[3][4];
  #pragma unroll
  for (int j = 0; j < 3; j++) {
    int kk = k0 + j;
    sb[j] = *(const short8*)(bp + kk*32);
    #pragma unroll
    for (int t = 0; t < 4; t++) sh[j][t] = heR[t][kk];
  }

  #pragma unroll 1
  for (int base = 0; base < 15; base += 3) {
    #pragma unroll
    for (int j = 0; j < 3; j++) {
      const int s = base + j;
      short8 cb = sb[j];
      #pragma unroll
      for (int t = 0; t < 4; t++) {
        float hk = sh[j][t];
        AFrag a;
        #pragma unroll
        for (int i = 0; i < 4; i++) a.u[i] = pkt(xs[t][i]*hk);
        c[t] = __builtin_amdgcn_mfma_f32_16x16x32_bf16(a.v, cb, c[t], 0, 0, 0);
      }
      int sn = s + 3;
      int kkn = (sn >= 16) ? 32 : (k0 + sn);
      sb[j] = *(const short8*)(bp + kkn*32);
      #pragma unroll
      for (int t = 0; t < 4; t++) sh[j][t] = heR[t][kkn];
    }
  }
  // tail: s=15 (j=0) always; s=16 (j=1) only khalf0 (bias row)
  {
    short8 cb = sb[0];
    #pragma unroll
    for (int t = 0; t < 4; t++) {
      float hk = sh[0][t];
      AFrag a;
      #pragma unroll
      for (int i = 0; i < 4; i++) a.u[i] = pkt(xs[t][i]*hk);
      c[t] = __builtin_amdgcn_mfma_f32_16x16x32_bf16(a.v, cb, c[t], 0, 0, 0);
    }
  }
  if (khalf == 0) {
    short8 cb = sb[1];
    #pragma unroll
    for (int t = 0; t < 4; t++) {
      float hk = sh[1][t];
      AFrag a;
      #pragma unroll
      for (int i = 0; i < 4; i++) a.u[i] = pkt(xs[t][i]*hk);
      c[t] = __builtin_amdgcn_mfma_f32_16x16x32_bf16(a.v, cb, c[t], 0, 0, 0);
    }
  }

  // cross-wave reduce: khalf1 dumps partials, khalf0 adds + stores bf16 in CSR order
  if (khalf == 1) {
    #pragma unroll
    for (int t = 0; t < 4; t++) {
      #pragma unroll
      for (int r = 0; r < 4; r++) {
        int el = t*16 + quad*4 + r;
        sRED[(nhalf*64 + el)*17 + nn] = c[t][r];
      }
    }
  }
  __syncthreads();
  if (khalf == 0) {
    #pragma unroll
    for (int t = 0; t < 4; t++) {
      #pragma unroll
      for (int r = 0; r < 4; r++) {
        int el = t*16 + quad*4 + r;
        float v = c[t][r] + sRED[(nhalf*64 + el)*17 + nn];
        msgB[(size_t)sPOS[el]*HID + nhalf*16 + nn] = bfbits(v);
      }
    }
  }
}

// hout = relu( (mean of CSR-contiguous bf16 msg rows) + hin @ root_w + root_b )
__global__ void k_gather(const unsigned short* __restrict__ msgB,
                         const int* __restrict__ off,
                         const float* __restrict__ hin,
                         const float* __restrict__ rw,
                         const float* __restrict__ rb,
                         float* __restrict__ hout) {
  __shared__ float rws[HID*HID];
  __shared__ float rbs[HID];
  for (int i = threadIdx.x; i < HID*HID; i += 256) rws[i] = rw[i];
  if (threadIdx.x < HID) rbs[threadIdx.x] = rb[threadIdx.x];
  __syncthreads();
  int t = blockIdx.x*256 + threadIdx.x;
  if (t >= N_NODES*8) return;
  int n = t >> 3, oc = t & 7;
  int s0 = off[n], s1 = off[n+1];
  float a0 = 0.f, a1 = 0.f, a2 = 0.f, a3 = 0.f;
  for (int j = s0; j < s1; j++) {            // contiguous bf16 rows
    uint2 u = *(const uint2*)(msgB + (size_t)j*HID + oc*4);
    a0 += __uint_as_float(u.x << 16);
    a1 += __uint_as_float(u.x & 0xffff0000u);
    a2 += __uint_as_float(u.y << 16);
    a3 += __uint_as_float(u.y & 0xffff0000u);
  }
  float inv = 1.f / fmaxf((float)(s1 - s0), 1.f);
  a0 = fmaf(a0, inv, rbs[oc*4+0]);
  a1 = fmaf(a1, inv, rbs[oc*4+1]);
  a2 = fmaf(a2, inv, rbs[oc*4+2]);
  a3 = fmaf(a3, inv, rbs[oc*4+3]);
  const float4* hp = (const float4*)(hin + (size_t)n*HID);
  #pragma unroll
  for (int jq = 0; jq < 8; jq++) {
    float4 hv = hp[jq];
    #pragma unroll
    for (int c = 0; c < 4; c++) {
      int j = jq*4 + c;
      float h = (c==0)?hv.x:(c==1)?hv.y:(c==2)?hv.z:hv.w;
      const float4* rp = (const float4*)(rws + j*HID + oc*4);
      float4 r = rp[0];
      a0 = fmaf(h, r.x, a0);
      a1 = fmaf(h, r.y, a1);
      a2 = fmaf(h, r.z, a2);
      a3 = fmaf(h, r.w, a3);
    }
  }
  float4 res = make_float4(fmaxf(a0,0.f), fmaxf(a1,0.f), fmaxf(a2,0.f), fmaxf(a3,0.f));
  ((float4*)(hout + (size_t)n*HID))[oc] = res;
}

// out = (relu((h@lo_w+lo_b)@d1_w+d1_b))@d2_w+d2_b   (no relu on z)
__global__ void k_decoder(const float* __restrict__ h,
                          const float* __restrict__ lo_w, const float* __restrict__ lo_b,
                          const float* __restrict__ d1_w, const float* __restrict__ d1_b,
                          const float* __restrict__ d2_w, const float* __restrict__ d2_b,
                          float* __restrict__ out) {
  __shared__ float lows[HID*LAT], lobs[LAT], d1s[LAT*HID], d1bs[HID], d2s[HID*NODE_F], d2bs[NODE_F];
  for (int i = threadIdx.x; i < HID*LAT; i += 256) lows[i] = lo_w[i];
  for (int i = threadIdx.x; i < LAT; i += 256) lobs[i] = lo_b[i];
  for (int i = threadIdx.x; i < LAT*HID; i += 256) d1s[i] = d1_w[i];
  for (int i = threadIdx.x; i < HID; i += 256) d1bs[i] = d1_b[i];
  for (int i = threadIdx.x; i < HID*NODE_F; i += 256) d2s[i] = d2_w[i];
  for (int i = threadIdx.x; i < NODE_F; i += 256) d2bs[i] = d2_b[i];
  __syncthreads();
  int n = blockIdx.x*256 + threadIdx.x;
  if (n >= N_NODES) return;
  float hr[HID];
  const float4* hp = (const float4*)(h + (size_t)n*HID);
  #pragma unroll
  for (int i = 0; i < HID/4; i++) { float4 v = hp[i]; hr[4*i]=v.x; hr[4*i+1]=v.y; hr[4*i+2]=v.z; hr[4*i+3]=v.w; }
  float z[LAT];
  #pragma unroll
  for (int o = 0; o < LAT; o++) {
    float a = lobs[o];
    #pragma unroll
    for (int j = 0; j < HID; j++) a = fmaf(hr[j], lows[j*LAT+o], a);
    z[o] = a;
  }
  float d[HID];
  #pragma unroll
  for (int o = 0; o < HID; o++) {
    float a = d1bs[o];
    #pragma unroll
    for (int j = 0; j < LAT; j++) a = fmaf(z[j], d1s[j*HID+o], a);
    d[o] = fmaxf(a, 0.f);
  }
  float* op = out + (size_t)n*NODE_F;
  #pragma unroll 8
  for (int o = 0; o < NODE_F; o++) {
    float a = d2bs[o];
    #pragma unroll
    for (int j = 0; j < HID; j++) a = fmaf(d[j], d2s[j*NODE_F+o], a);
    op[o] = a;
  }
}

extern "C" void kernel_launch(void* const* d_in, const int* in_sizes, int n_in,
                              void* d_out, int out_size, void* d_ws, size_t ws_size,
                              hipStream_t stream) {
  const float* x   = (const float*)d_in[0];
  const int*   ei  = (const int*)d_in[1];
  const float* ea  = (const float*)d_in[2];
  const float* liw = (const float*)d_in[3];
  const float* lib = (const float*)d_in[4];
  const float* ew1 = (const float*)d_in[5];
  const float* eb1 = (const float*)d_in[6];
  const float* ew2 = (const float*)d_in[7];
  const float* eb2 = (const float*)d_in[8];
  const float* rw  = (const float*)d_in[9];
  const float* rb  = (const float*)d_in[10];
  const float* low = (const float*)d_in[11];
  const float* lob = (const float*)d_in[12];
  const float* d1w = (const float*)d_in[13];
  const float* d1b = (const float*)d_in[14];
  const float* d2w = (const float*)d_in[15];
  const float* d2b = (const float*)d_in[16];
  float* out = (float*)d_out;

  float* h0   = (float*)d_ws;                          // 1.6M f
  float* h1   = h0  + (size_t)N_NODES*HID;             // 1.6M f
  unsigned short* msgB = (unsigned short*)(h1 + (size_t)N_NODES*HID);  // 6.4M bf16 (CSR-ordered)
  int*  deg   = (int*)(msgB + (size_t)N_EDGES*HID);    // 50k
  int*  off   = deg + N_NODES;                         // 50k+1 (alloc 50016)
  int*  cursor= off + N_NODES + 16;                    // 50k
  int*  cpos  = cursor + N_NODES;                      // 200k
  int*  bsum  = cpos + N_EDGES;                        // 256
  unsigned short* w2t = (unsigned short*)(bsum + 256); // 3*32*1056 bf16
  unsigned short* w1p = w2t + 3*HID*KTOT;              // 3*1024 bf16

  k_prep<<<(3*HID*KTOT)/256, 256, 0, stream>>>(ew2, eb2, ew1, w2t, w1p, deg);
  k_hist<<<(N_EDGES + 255)/256, 256, 0, stream>>>(ei, deg);
  k_scan1<<<SCAN_BLOCKS, 256, 0, stream>>>(deg, off, bsum);
  k_scan23<<<SCAN_BLOCKS, 256, 0, stream>>>(off, bsum, cursor);
  k_scatter<<<(N_EDGES + 255)/256, 256, 0, stream>>>(ei, off, cursor, cpos);

  k_lin_in<<<(N_NODES*HID + 255)/256, 256, 0, stream>>>(x, liw, lib, h0);

  float* hin = h0; float* hout = h1;
  for (int i = 0; i < 3; i++) {
    k_msg<<<N_EDGES/64, 256, 0, stream>>>(hin, ea, ei,
        w1p + (size_t)i*1024, eb1 + i*HID,
        w2t + (size_t)i*HID*KTOT, cpos, msgB);
    k_gather<<<(N_NODES*8 + 255)/256, 256, 0, stream>>>(msgB, off, hin,
        rw + i*HID*HID, rb + i*HID, hout);
    float* t = hin; hin = hout; hout = t;
  }

  k_decoder<<<(N_NODES + 255)/256, 256, 0, stream>>>(hin, low, lob, d1w, d1b, d2w, d2b, out);
}

// Round 14
// 276.606 us; speedup vs baseline: 1.1051x; 1.1051x over previous
//
#include <hip/hip_runtime.h>
#include <hip/hip_bf16.h>
#include <stdint.h>

#define N_NODES 50000
#define N_EDGES 200000
#define NODE_F 64
#define EDGE_F 16
#define HID 32
#define LAT 16
#define KTOT 1056   // 1024 + 32 (b2 folded in as 33rd K-tile)
#define SCAN_BLOCKS 196   // 196*256 = 50176 >= 50000

typedef __attribute__((ext_vector_type(8))) short short8;   // 8 bf16 = 4 VGPR
typedef __attribute__((ext_vector_type(4))) float f32x4;
typedef __attribute__((ext_vector_type(2))) float f32x2;

static __device__ __forceinline__ unsigned short bfbits(float f) {
  union { __hip_bfloat16 h; unsigned short s; } c; c.h = __float2bfloat16(f); return c.s;
}
// Truncation pack: 1x v_perm_b32. lo16 = top of bits(v.x), hi16 = top of bits(v.y).
static __device__ __forceinline__ unsigned pkt(f32x2 v) {
  return __builtin_amdgcn_perm(__float_as_uint(v.y), __float_as_uint(v.x), 0x07060302u);
}
union AFrag { short8 v; unsigned u[4]; };

// --- prep: w2 transpose to bf16 B-layout, w1 packed into per-lane B-fragments,
//     deg zeroing (all fused, once per call) ---
__global__ void k_prep(const float* __restrict__ ew2, const float* __restrict__ eb2,
                       const float* __restrict__ ew1,
                       unsigned short* __restrict__ w2t,
                       unsigned short* __restrict__ w1p,
                       int* __restrict__ deg) {
  int g = blockIdx.x*256 + threadIdx.x;          // 396*256 = 101376 exactly
  int l = g / (HID*KTOT);
  int r = g % (HID*KTOT);
  int o = r / KTOT;
  int kg = r % KTOT;
  int k = kg >> 5, h = kg & 31;
  float v = (k < 32) ? ew2[(size_t)l*32768 + k*1024 + h*32 + o]
                     : eb2[(size_t)l*1024 + h*32 + o];
  w2t[g] = bfbits(v);
  if (g < N_NODES) deg[g] = 0;
  // w1p[l][nt][lane][j] = B-frag element B[k=(lane>>4)*8+j][n=nt*16+(lane&15)]
  if (g < 3*2*64*8) {
    int l2 = g >> 10;
    int r2 = g & 1023;
    int nt = r2 >> 9;
    int ln = (r2 >> 3) & 63;
    int j  = r2 & 7;
    int kgr = ln >> 4;
    float w = (kgr < 2) ? ew1[(size_t)l2*512 + (kgr*8 + j)*32 + nt*16 + (ln & 15)] : 0.f;
    w1p[g] = bfbits(w);
  }
}

__global__ void k_hist(const int* __restrict__ ei, int* __restrict__ deg) {
  int t = blockIdx.x*256 + threadIdx.x;
  if (t >= N_EDGES) return;
  int d = ei[N_EDGES + t];
  d = min(max(d, 0), N_NODES-1);
  atomicAdd(&deg[d], 1);
}

__global__ __launch_bounds__(256) void k_scan1(const int* __restrict__ deg,
                                               int* __restrict__ off,
                                               int* __restrict__ bsum) {
  __shared__ int s[256];
  const int tid = threadIdx.x;
  const int t = blockIdx.x*256 + tid;
  int d = (t < N_NODES) ? deg[t] : 0;
  s[tid] = d; __syncthreads();
  int v = d;
  #pragma unroll
  for (int ofs = 1; ofs < 256; ofs <<= 1) {
    int w = (tid >= ofs) ? s[tid-ofs] : 0;
    __syncthreads();
    v += w; s[tid] = v;
    __syncthreads();
  }
  if (t < N_NODES) off[t] = v - d;
  if (tid == 255) bsum[blockIdx.x] = v;
}

// fused scan2+scan3: each block computes its bsum prefix in-wave, applies, zeroes cursor
__global__ __launch_bounds__(256) void k_scan23(int* __restrict__ off,
                                                const int* __restrict__ bsum,
                                                int* __restrict__ cursor) {
  __shared__ int sPref;
  const int tid = threadIdx.x;
  const int b = blockIdx.x;
  if (tid < 64) {
    int acc = 0;
    for (int i = tid; i < b; i += 64) acc += bsum[i];
    #pragma unroll
    for (int o = 32; o; o >>= 1) acc += __shfl_down(acc, o);
    if (tid == 0) sPref = acc;
  }
  __syncthreads();
  int pref = sPref;
  int t = b*256 + tid;
  if (t < N_NODES) {
    off[t] += pref;
    cursor[t] = 0;
  }
  if (t == 0) off[N_NODES] = N_EDGES;
}

// emits csr_pos only: csr_pos[e] = slot of edge e in CSR order
__global__ void k_scatter(const int* __restrict__ ei, const int* __restrict__ off,
                          int* __restrict__ cursor, int* __restrict__ csr_pos) {
  int t = blockIdx.x*256 + threadIdx.x;
  if (t >= N_EDGES) return;
  int d = ei[N_EDGES + t];
  d = min(max(d, 0), N_NODES-1);
  int pos = atomicAdd(&cursor[d], 1);
  csr_pos[t] = off[d] + pos;
}

// h = relu(x @ W + b)
__global__ void k_lin_in(const float* __restrict__ x,
                         const float* __restrict__ W,
                         const float* __restrict__ b,
                         float* __restrict__ h) {
  __shared__ float Ws[NODE_F*HID];
  __shared__ float bs[HID];
  for (int i = threadIdx.x; i < NODE_F*HID; i += 256) Ws[i] = W[i];
  if (threadIdx.x < HID) bs[threadIdx.x] = b[threadIdx.x];
  __syncthreads();
  int t = blockIdx.x*256 + threadIdx.x;
  if (t >= N_NODES*HID) return;
  int n = t >> 5, o = t & 31;
  const float4* xp = (const float4*)(x + (size_t)n*NODE_F);
  float acc = bs[o];
  #pragma unroll
  for (int j = 0; j < NODE_F/4; j++) {
    float4 v = xp[j];
    acc = fmaf(v.x, Ws[(4*j+0)*HID+o], acc);
    acc = fmaf(v.y, Ws[(4*j+1)*HID+o], acc);
    acc = fmaf(v.z, Ws[(4*j+2)*HID+o], acc);
    acc = fmaf(v.w, Ws[(4*j+3)*HID+o], acc);
  }
  h[t] = fmaxf(acc, 0.f);
}

// MFMA msg kernel (R12 shape: proven fastest). 256 edges/block, 4 waves,
// 64 edges (4 M-tiles) per wave, NO barriers; depth-3 pipelined 33-step K-loop.
// Single change vs R12: store bf16 (halves WRITE_SIZE), CSR-ordered via csr_pos.
__global__ __launch_bounds__(256) void k_msg(const float* __restrict__ hin,
                                             const float* __restrict__ ea,
                                             const int* __restrict__ ei,
                                             const unsigned short* __restrict__ w1pl,
                                             const float* __restrict__ b1,
                                             const unsigned short* __restrict__ w2tl,
                                             const int* __restrict__ csr_pos,
                                             unsigned short* __restrict__ msgB) {
  __shared__ float sHE[256*33];   // he[e][0..32], stride 33  (33.8 KB)
  __shared__ int   sSRC[256];
  __shared__ int   sPOS[256];
  const int tid = threadIdx.x;
  const int be  = blockIdx.x*256;
  const int wv   = tid >> 6;          // wave 0..3
  const int lane = tid & 63;
  const int nn   = lane & 15;
  const int quad = lane >> 4;
  const int wbase = wv*64;            // this wave's 64 edges (local)

  // per-wave staging of src/pos + bias K-row (all lanes)
  {
    int el = wbase + lane;
    int e = min(be + el, N_EDGES-1);
    sSRC[el] = min(max(ei[e], 0), N_NODES-1);
    sPOS[el] = csr_pos[e];
    sHE[el*33 + 32] = 1.0f;
  }

  // --- he via MFMA: 4 M-tiles x 2 N-halves (wave-internal) ---
  {
    short8 wb0 = *(const short8*)(w1pl + lane*8);         // nt=0
    short8 wb1 = *(const short8*)(w1pl + 512 + lane*8);   // nt=1
    f32x4 z = {0.f,0.f,0.f,0.f};
    float bv0 = b1[nn], bv1 = b1[nn + 16];
    #pragma unroll
    for (int t = 0; t < 4; t++) {
      AFrag a;
      if (quad < 2) {
        int e = min(be + wbase + t*16 + nn, N_EDGES-1);
        const float4* p = (const float4*)(ea + (size_t)e*EDGE_F + quad*8);
        float4 u = p[0], v = p[1];
        a.u[0] = pkt(f32x2{u.x,u.y}); a.u[1] = pkt(f32x2{u.z,u.w});
        a.u[2] = pkt(f32x2{v.x,v.y}); a.u[3] = pkt(f32x2{v.z,v.w});
      } else {
        #pragma unroll
        for (int i = 0; i < 4; i++) a.u[i] = 0u;
      }
      f32x4 h0 = __builtin_amdgcn_mfma_f32_16x16x32_bf16(a.v, wb0, z, 0, 0, 0);
      f32x4 h1 = __builtin_amdgcn_mfma_f32_16x16x32_bf16(a.v, wb1, z, 0, 0, 0);
      #pragma unroll
      for (int r = 0; r < 4; r++) {
        int ro = (wbase + t*16 + quad*4 + r)*33;
        sHE[ro + nn]      = fmaxf(h0[r] + bv0, 0.f);
        sHE[ro + 16 + nn] = fmaxf(h1[r] + bv1, 0.f);
      }
    }
  }
  // no __syncthreads: all LDS producer/consumer pairs are wave-internal

  // xs from global (L2-hot), 4 tiles
  f32x2 xs[4][4];
  #pragma unroll
  for (int t = 0; t < 4; t++) {
    int si = sSRC[wbase + t*16 + nn];
    const float4* p = (const float4*)(hin + (size_t)si*HID);
    float4 a = p[quad*2], b = p[quad*2+1];
    xs[t][0] = f32x2{a.x, a.y}; xs[t][1] = f32x2{a.z, a.w};
    xs[t][2] = f32x2{b.x, b.y}; xs[t][3] = f32x2{b.z, b.w};
  }

  f32x4 c0[4], c1[4];
  #pragma unroll
  for (int t = 0; t < 4; t++) { c0[t] = f32x4{0.f,0.f,0.f,0.f}; c1[t] = c0[t]; }

  const unsigned short* bp0 = w2tl + (unsigned)nn*KTOT + quad*8;
  const unsigned short* bp1 = bp0 + 16*KTOT;
  const float* heR[4];
  #pragma unroll
  for (int t = 0; t < 4; t++) heR[t] = sHE + (wbase + t*16 + nn)*33;

  // depth-3 pipeline slots
  short8 sb0[3], sb1[3];
  float  sh[3][4];
  #pragma unroll
  for (int j = 0; j < 3; j++) {
    sb0[j] = *(const short8*)(bp0 + j*32);
    sb1[j] = *(const short8*)(bp1 + j*32);
    #pragma unroll
    for (int t = 0; t < 4; t++) sh[j][t] = heR[t][j];
  }

  #pragma unroll 1
  for (int base = 0; base < 30; base += 3) {
    #pragma unroll
    for (int j = 0; j < 3; j++) {
      const int kk = base + j;
      short8 cb0 = sb0[j], cb1 = sb1[j];
      #pragma unroll
      for (int t = 0; t < 4; t++) {
        float hk = sh[j][t];
        AFrag a;
        #pragma unroll
        for (int i = 0; i < 4; i++) a.u[i] = pkt(xs[t][i]*hk);
        c0[t] = __builtin_amdgcn_mfma_f32_16x16x32_bf16(a.v, cb0, c0[t], 0, 0, 0);
        c1[t] = __builtin_amdgcn_mfma_f32_16x16x32_bf16(a.v, cb1, c1[t], 0, 0, 0);
      }
      sb0[j] = *(const short8*)(bp0 + (kk+3)*32);
      sb1[j] = *(const short8*)(bp1 + (kk+3)*32);
      #pragma unroll
      for (int t = 0; t < 4; t++) sh[j][t] = heR[t][kk+3];
    }
  }
  #pragma unroll
  for (int j = 0; j < 3; j++) {
    short8 cb0 = sb0[j], cb1 = sb1[j];
    #pragma unroll
    for (int t = 0; t < 4; t++) {
      float hk = sh[j][t];
      AFrag a;
      #pragma unroll
      for (int i = 0; i < 4; i++) a.u[i] = pkt(xs[t][i]*hk);
      c0[t] = __builtin_amdgcn_mfma_f32_16x16x32_bf16(a.v, cb0, c0[t], 0, 0, 0);
      c1[t] = __builtin_amdgcn_mfma_f32_16x16x32_bf16(a.v, cb1, c1[t], 0, 0, 0);
    }
  }

  // store bf16 in CSR order: row = csr_pos[e]
  #pragma unroll
  for (int t = 0; t < 4; t++) {
    #pragma unroll
    for (int r = 0; r < 4; r++) {
      int el = wbase + t*16 + quad*4 + r;
      if (be + el < N_EDGES) {
        size_t row = (size_t)sPOS[el]*HID;
        msgB[row +      nn] = bfbits(c0[t][r]);
        msgB[row + 16 + nn] = bfbits(c1[t][r]);
      }
    }
  }
}

// hout = relu( (mean of CSR-contiguous bf16 msg rows) + hin @ root_w + root_b )
__global__ void k_gather(const unsigned short* __restrict__ msgB,
                         const int* __restrict__ off,
                         const float* __restrict__ hin,
                         const float* __restrict__ rw,
                         const float* __restrict__ rb,
                         float* __restrict__ hout) {
  __shared__ float rws[HID*HID];
  __shared__ float rbs[HID];
  for (int i = threadIdx.x; i < HID*HID; i += 256) rws[i] = rw[i];
  if (threadIdx.x < HID) rbs[threadIdx.x] = rb[threadIdx.x];
  __syncthreads();
  int t = blockIdx.x*256 + threadIdx.x;
  if (t >= N_NODES*8) return;
  int n = t >> 3, oc = t & 7;
  int s0 = off[n], s1 = off[n+1];
  float a0 = 0.f, a1 = 0.f, a2 = 0.f, a3 = 0.f;
  for (int j = s0; j < s1; j++) {            // contiguous bf16 rows
    uint2 u = *(const uint2*)(msgB + (size_t)j*HID + oc*4);
    a0 += __uint_as_float(u.x << 16);
    a1 += __uint_as_float(u.x & 0xffff0000u);
    a2 += __uint_as_float(u.y << 16);
    a3 += __uint_as_float(u.y & 0xffff0000u);
  }
  float inv = 1.f / fmaxf((float)(s1 - s0), 1.f);
  a0 = fmaf(a0, inv, rbs[oc*4+0]);
  a1 = fmaf(a1, inv, rbs[oc*4+1]);
  a2 = fmaf(a2, inv, rbs[oc*4+2]);
  a3 = fmaf(a3, inv, rbs[oc*4+3]);
  const float4* hp = (const float4*)(hin + (size_t)n*HID);
  #pragma unroll
  for (int jq = 0; jq < 8; jq++) {
    float4 hv = hp[jq];
    #pragma unroll
    for (int c = 0; c < 4; c++) {
      int j = jq*4 + c;
      float h = (c==0)?hv.x:(c==1)?hv.y:(c==2)?hv.z:hv.w;
      const float4* rp = (const float4*)(rws + j*HID + oc*4);
      float4 r = rp[0];
      a0 = fmaf(h, r.x, a0);
      a1 = fmaf(h, r.y, a1);
      a2 = fmaf(h, r.z, a2);
      a3 = fmaf(h, r.w, a3);
    }
  }
  float4 res = make_float4(fmaxf(a0,0.f), fmaxf(a1,0.f), fmaxf(a2,0.f), fmaxf(a3,0.f));
  ((float4*)(hout + (size_t)n*HID))[oc] = res;
}

// out = (relu((h@lo_w+lo_b)@d1_w+d1_b))@d2_w+d2_b   (no relu on z)
__global__ void k_decoder(const float* __restrict__ h,
                          const float* __restrict__ lo_w, const float* __restrict__ lo_b,
                          const float* __restrict__ d1_w, const float* __restrict__ d1_b,
                          const float* __restrict__ d2_w, const float* __restrict__ d2_b,
                          float* __restrict__ out) {
  __shared__ float lows[HID*LAT], lobs[LAT], d1s[LAT*HID], d1bs[HID], d2s[HID*NODE_F], d2bs[NODE_F];
  for (int i = threadIdx.x; i < HID*LAT; i += 256) lows[i] = lo_w[i];
  for (int i = threadIdx.x; i < LAT; i += 256) lobs[i] = lo_b[i];
  for (int i = threadIdx.x; i < LAT*HID; i += 256) d1s[i] = d1_w[i];
  for (int i = threadIdx.x; i < HID; i += 256) d1bs[i] = d1_b[i];
  for (int i = threadIdx.x; i < HID*NODE_F; i += 256) d2s[i] = d2_w[i];
  for (int i = threadIdx.x; i < NODE_F; i += 256) d2bs[i] = d2_b[i];
  __syncthreads();
  int n = blockIdx.x*256 + threadIdx.x;
  if (n >= N_NODES) return;
  float hr[HID];
  const float4* hp = (const float4*)(h + (size_t)n*HID);
  #pragma unroll
  for (int i = 0; i < HID/4; i++) { float4 v = hp[i]; hr[4*i]=v.x; hr[4*i+1]=v.y; hr[4*i+2]=v.z; hr[4*i+3]=v.w; }
  float z[LAT];
  #pragma unroll
  for (int o = 0; o < LAT; o++) {
    float a = lobs[o];
    #pragma unroll
    for (int j = 0; j < HID; j++) a = fmaf(hr[j], lows[j*LAT+o], a);
    z[o] = a;
  }
  float d[HID];
  #pragma unroll
  for (int o = 0; o < HID; o++) {
    float a = d1bs[o];
    #pragma unroll
    for (int j = 0; j < LAT; j++) a = fmaf(z[j], d1s[j*HID+o], a);
    d[o] = fmaxf(a, 0.f);
  }
  float* op = out + (size_t)n*NODE_F;
  #pragma unroll 8
  for (int o = 0; o < NODE_F; o++) {
    float a = d2bs[o];
    #pragma unroll
    for (int j = 0; j < HID; j++) a = fmaf(d[j], d2s[j*NODE_F+o], a);
    op[o] = a;
  }
}

extern "C" void kernel_launch(void* const* d_in, const int* in_sizes, int n_in,
                              void* d_out, int out_size, void* d_ws, size_t ws_size,
                              hipStream_t stream) {
  const float* x   = (const float*)d_in[0];
  const int*   ei  = (const int*)d_in[1];
  const float* ea  = (const float*)d_in[2];
  const float* liw = (const float*)d_in[3];
  const float* lib = (const float*)d_in[4];
  const float* ew1 = (const float*)d_in[5];
  const float* eb1 = (const float*)d_in[6];
  const float* ew2 = (const float*)d_in[7];
  const float* eb2 = (const float*)d_in[8];
  const float* rw  = (const float*)d_in[9];
  const float* rb  = (const float*)d_in[10];
  const float* low = (const float*)d_in[11];
  const float* lob = (const float*)d_in[12];
  const float* d1w = (const float*)d_in[13];
  const float* d1b = (const float*)d_in[14];
  const float* d2w = (const float*)d_in[15];
  const float* d2b = (const float*)d_in[16];
  float* out = (float*)d_out;

  float* h0   = (float*)d_ws;                          // 1.6M f
  float* h1   = h0  + (size_t)N_NODES*HID;             // 1.6M f
  unsigned short* msgB = (unsigned short*)(h1 + (size_t)N_NODES*HID);  // 6.4M bf16 (CSR-ordered)
  int*  deg   = (int*)(msgB + (size_t)N_EDGES*HID);    // 50k
  int*  off   = deg + N_NODES;                         // 50k+1 (alloc 50016)
  int*  cursor= off + N_NODES + 16;                    // 50k
  int*  cpos  = cursor + N_NODES;                      // 200k
  int*  bsum  = cpos + N_EDGES;                        // 256
  unsigned short* w2t = (unsigned short*)(bsum + 256); // 3*32*1056 bf16
  unsigned short* w1p = w2t + 3*HID*KTOT;              // 3*1024 bf16

  k_prep<<<(3*HID*KTOT)/256, 256, 0, stream>>>(ew2, eb2, ew1, w2t, w1p, deg);
  k_hist<<<(N_EDGES + 255)/256, 256, 0, stream>>>(ei, deg);
  k_scan1<<<SCAN_BLOCKS, 256, 0, stream>>>(deg, off, bsum);
  k_scan23<<<SCAN_BLOCKS, 256, 0, stream>>>(off, bsum, cursor);
  k_scatter<<<(N_EDGES + 255)/256, 256, 0, stream>>>(ei, off, cursor, cpos);

  k_lin_in<<<(N_NODES*HID + 255)/256, 256, 0, stream>>>(x, liw, lib, h0);

  float* hin = h0; float* hout = h1;
  for (int i = 0; i < 3; i++) {
    k_msg<<<(N_EDGES + 255)/256, 256, 0, stream>>>(hin, ea, ei,
        w1p + (size_t)i*1024, eb1 + i*HID,
        w2t + (size_t)i*HID*KTOT, cpos, msgB);
    k_gather<<<(N_NODES*8 + 255)/256, 256, 0, stream>>>(msgB, off, hin,
        rw + i*HID*HID, rb + i*HID, hout);
    float* t = hin; hin = hout; hout = t;
  }

  k_decoder<<<(N_NODES + 255)/256, 256, 0, stream>>>(hin, low, lob, d1w, d1b, d2w, d2b, out);
}